// Round 7
// baseline (425.551 us; speedup 1.0000x reference)
//
#include <hip/hip_runtime.h>
#include <cstdint>
#include <cstddef>

typedef __bf16 bf16;
typedef __attribute__((ext_vector_type(8))) __bf16 bf16x8;
typedef __attribute__((ext_vector_type(4))) __bf16 bf16x4;
typedef __attribute__((ext_vector_type(4))) float f32x4;

#define ATT_SCALE 0.125f   // 1/sqrt(64)
#define NEG_BIG  -1000000000.0f

__device__ __forceinline__ f32x4 mfma16(bf16x8 a, bf16x8 b, f32x4 c) {
  return __builtin_amdgcn_mfma_f32_16x16x32_bf16(a, b, c, 0, 0, 0);
}

__device__ __forceinline__ void gload16(const bf16* g, bf16* l) {
  __builtin_amdgcn_global_load_lds((__attribute__((address_space(1))) void*)g,
                                   (__attribute__((address_space(3))) void*)l,
                                   16, 0, 0);
}

// ---------------- fused prep: all fp32->bf16 converts + RoPE table ----------------
__global__ __launch_bounds__(256) void prep_all(const float* __restrict__ hs,
                                                const float* __restrict__ Wq,
                                                const float* __restrict__ Wk,
                                                const float* __restrict__ Wv,
                                                const float* __restrict__ Wo,
                                                bf16* __restrict__ hs16, bf16* __restrict__ wq16,
                                                bf16* __restrict__ wk16, bf16* __restrict__ wv16,
                                                bf16* __restrict__ wo16,
                                                float* __restrict__ cosT, float* __restrict__ sinT) {
  int b = blockIdx.x, t = threadIdx.x;
  const float* src; bf16* dst; int i;
  if (b < 16384)      { src = hs; dst = hs16; i = b * 256 + t; }
  else if (b < 20480) { src = Wq; dst = wq16; i = (b - 16384) * 256 + t; }
  else if (b < 21504) { src = Wk; dst = wk16; i = (b - 20480) * 256 + t; }
  else if (b < 22528) { src = Wv; dst = wv16; i = (b - 21504) * 256 + t; }
  else if (b < 26624) { src = Wo; dst = wo16; i = (b - 22528) * 256 + t; }
  else {
    int idx = (b - 26624) * 256 + t;   // 8192*32
    int tt = idx >> 5, j = idx & 31;
    float inv = exp2f(-(float)j * (13.287712379549449f / 32.0f));
    float fr = (float)tt * inv;
    cosT[idx] = cosf(fr); sinT[idx] = sinf(fr);
    return;
  }
  float4 v = *((const float4*)src + i);
  bf16x4 o;
  o[0] = (bf16)v.x; o[1] = (bf16)v.y; o[2] = (bf16)v.z; o[3] = (bf16)v.w;
  *((bf16x4*)dst + i) = o;
}

// ---------------- 256x256 bf16 GEMM: A via LDS pipeline, B direct global->reg ----
// C[m,n] = sum_k A[m,k]*B[n,k]. BK=32, 512 threads = 8 waves (2M x 4N),
// per-wave out 128x64 (acc[8][4]). LDS: A-only, 4-buffer rotation 4x16 KB = 64 KB.
// B fragments gathered per-lane from global (weights are L2/L1-resident; each
// 128B line fully consumed by the wave) and prefetched 1 tile ahead into
// ping-pong reg sets bA/bB (even/odd kt). Removes B from LDS: LDS traffic/CU/tile
// 96->64 KB, below the MFMA budget (~310 cy) -> MFMA-bound.
// vmcnt ledger (A-guard only; B RAW is compiler-guarded and A is always oldest):
//   prologue issue A0,B0,A1,A2 -> tile0 waits vmcnt(4); steady tiles issue
//   {B(kt+1)x4, A(kt+3)x2} -> entry wait vmcnt(2); last two tiles vmcnt(0).
// A chunk swizzle unchanged (0 conflicts): row r storage chunk p holds logical
// chunk p^((r>>1)&3); applied on GLOBAL source, LDS dest linear, reads same XOR.
template <int BSEL, int OUTF32, int ROPE>
__global__ __launch_bounds__(512, 2) void gemm256(const bf16* __restrict__ A,
                                                  const bf16* __restrict__ B0,
                                                  const bf16* __restrict__ B1,
                                                  const bf16* __restrict__ B2,
                                                  void* __restrict__ Cout,
                                                  const float* __restrict__ cosT,
                                                  const float* __restrict__ sinT,
                                                  int N, int K) {
  __shared__ bf16 As[4][8192];   // [buf][256 rows x 32 k]
  const int tid = threadIdx.x, lane = tid & 63, wid = tid >> 6;
  const int m0 = blockIdx.x * 256, n0 = blockIdx.y * 256;

  const int wr = wid >> 2, wc = wid & 3;
  const int fr = lane & 15, g4 = lane >> 4;
  const int sw8 = (g4 ^ ((fr >> 1) & 3)) * 8;

  f32x4 acc[8][4] = {};

  auto brow = [&](int n) -> const bf16* {
    if (BSEL) {
      if (n < 2048) return B0 + (size_t)n * K;
      if (n < 2560) return B1 + (size_t)(n - 2048) * K;
      return B2 + (size_t)(n - 2560) * K;
    }
    return B0 + (size_t)n * K;
  };

  // A staging sources (chunk-swizzled global addresses, linear LDS dest)
  const int r0 = tid >> 2, r1 = 128 + (tid >> 2);
  const int l0 = (tid & 3) ^ ((r0 >> 1) & 3);
  const int l1 = (tid & 3) ^ ((r1 >> 1) & 3);
  const bf16* aS0 = A + (size_t)(m0 + r0) * K + l0 * 8;
  const bf16* aS1 = A + (size_t)(m0 + r1) * K + l1 * 8;
  const int st0 = wid * 512;          // elems; HW adds lane*16B
  const int st1 = 4096 + wid * 512;

  // B per-lane fragment base pointers (direct global)
  const bf16* bp[4];
#pragma unroll
  for (int nf = 0; nf < 4; ++nf)
    bp[nf] = brow(n0 + wc * 64 + nf * 16 + fr) + g4 * 8;

  bf16x8 bA[4], bB[4];

#define STAGE_A(KT) { \
    gload16(aS0 + (KT) * 32, &As[(KT) & 3][0] + st0); \
    gload16(aS1 + (KT) * 32, &As[(KT) & 3][0] + st1); }

#define TILE(KT, BCUR, BNXT, VM, STG, PF) { \
    asm volatile("s_waitcnt vmcnt(" VM ")" ::: "memory"); \
    __builtin_amdgcn_s_barrier(); \
    __builtin_amdgcn_sched_barrier(0); \
    const bf16* Ab = &As[(KT) & 3][0]; \
    bf16x8 af[4]; \
    _Pragma("unroll") for (int mf = 0; mf < 4; ++mf) \
      af[mf] = *(const bf16x8*)(Ab + (wr * 128 + mf * 16 + fr) * 32 + sw8); \
    if (PF) { _Pragma("unroll") for (int nf = 0; nf < 4; ++nf) \
      BNXT[nf] = *(const bf16x8*)(bp[nf] + ((KT) + 1) * 32); } \
    if (STG) STAGE_A((KT) + 3); \
    __builtin_amdgcn_s_setprio(1); \
    _Pragma("unroll") for (int mf = 0; mf < 4; ++mf) \
      _Pragma("unroll") for (int nf = 0; nf < 4; ++nf) \
        acc[mf][nf] = mfma16(af[mf], BCUR[nf], acc[mf][nf]); \
    __builtin_amdgcn_s_setprio(0); \
    _Pragma("unroll") for (int mf = 0; mf < 4; ++mf) \
      af[mf] = *(const bf16x8*)(Ab + (wr * 128 + 64 + mf * 16 + fr) * 32 + sw8); \
    __builtin_amdgcn_s_setprio(1); \
    _Pragma("unroll") for (int mf = 0; mf < 4; ++mf) \
      _Pragma("unroll") for (int nf = 0; nf < 4; ++nf) \
        acc[4 + mf][nf] = mfma16(af[mf], BCUR[nf], acc[4 + mf][nf]); \
    __builtin_amdgcn_s_setprio(0); \
  }

  // prologue: A(0), B(0)->bA, A(1), A(2)  [order matters for the ledger]
  STAGE_A(0);
#pragma unroll
  for (int nf = 0; nf < 4; ++nf) bA[nf] = *(const bf16x8*)(bp[nf]);
  STAGE_A(1);
  STAGE_A(2);

  const int NT = K >> 5;   // 64
  TILE(0, bA, bB, "4", 1, 1)
  for (int kt = 1; kt + 2 < NT - 1; kt += 2) {   // pairs (1,2)..(59,60)
    TILE(kt, bB, bA, "2", 1, 1)
    TILE(kt + 1, bA, bB, "2", 1, 1)
  }
  TILE(NT - 3, bB, bA, "2", 0, 1)   // 61: consume bB, prefetch B(62)->bA
  TILE(NT - 2, bA, bB, "0", 0, 1)   // 62: consume bA, prefetch B(63)->bB
  TILE(NT - 1, bB, bA, "0", 0, 0)   // 63: consume bB
#undef TILE
#undef STAGE_A

  // epilogue: acc[am] -> wave-tile row am*16 (am 0..3 = first 64-row half, 4..7 second)
  const int fc = lane & 15, fr4 = (lane >> 4) * 4;
  if (ROPE && (n0 + wc * 64) < 2560) {
#pragma unroll
    for (int am = 0; am < 8; ++am)
#pragma unroll
      for (int i = 0; i < 4; ++i) {
        size_t row = (size_t)(m0 + wr * 128 + am * 16 + fr4 + i);
        bf16* base = (bf16*)Cout + row * (size_t)N + n0 + wc * 64;
#pragma unroll
        for (int nf = 0; nf < 2; ++nf) {
          int j = nf * 16 + fc;
          float c = cosT[row * 32 + j], sn = sinT[row * 32 + j];
          float x1 = acc[am][nf][i], x2 = acc[am][nf + 2][i];
          base[j]      = (bf16)(x1 * c - x2 * sn);
          base[j + 32] = (bf16)(x2 * c + x1 * sn);
        }
      }
  } else {
#pragma unroll
    for (int am = 0; am < 8; ++am)
#pragma unroll
      for (int i = 0; i < 4; ++i) {
        size_t row = (size_t)(m0 + wr * 128 + am * 16 + fr4 + i);
#pragma unroll
        for (int nf = 0; nf < 4; ++nf) {
          int col = n0 + wc * 64 + nf * 16 + fc;
          if (OUTF32)
            ((float*)Cout)[row * (size_t)N + col] = acc[am][nf][i];
          else
            ((bf16*)Cout)[row * (size_t)N + col] = (bf16)acc[am][nf][i];
        }
      }
  }
}

// ---------------- block-sparse attention, GQA-grouped, pipelined ----------------
// (unchanged — validated)
__global__ __launch_bounds__(1024) void attn_sparse(const bf16* __restrict__ qkv,
                                                    bf16* __restrict__ attn) {
  const int iblk = blockIdx.x;
  const int kv = blockIdx.y;
  const int tid = threadIdx.x, lane = tid & 63, wid = tid >> 6;
  const int hloc = wid >> 2;
  const int h = kv * 4 + hloc;
  const int rg = wid & 3;

  __shared__ bf16 Ks[64 * 64];
  __shared__ bf16 Vt[2][64 * 72];
  __shared__ bf16 Ps[16 * 16 * 68];

  const int qcol = h * 64, kcol = 2048 + kv * 64, vcol = 2560 + kv * 64;
  const size_t trow0 = (size_t)iblk * 64;
  const int fr = lane & 15, g4 = lane >> 4, fk = g4 * 8, fr4 = g4 * 4;

  const bf16* qrow = qkv + (trow0 + rg * 16 + fr) * 3072 + qcol;
  bf16x8 bq0 = *(const bf16x8*)(qrow + fk);
  bf16x8 bq1 = *(const bf16x8*)(qrow + 32 + fk);

  float mrun = -INFINITY, lrun = 0.f;
  f32x4 acc[4] = {};

  const int kr = tid >> 3, ks = tid & 7;
  const int vu = tid & 511, vp = vu & 31, vd0 = (vu >> 5) * 4;
  const bool isK = (tid < 512);

  const int nsel = (iblk < 8) ? (iblk + 1) : 9;
  auto jof = [&](int js) { return (iblk < 8) ? js : ((js == 0) ? 0 : iblk - 8 + js); };

  {
    const size_t krow = (size_t)jof(0) * 64;
    if (isK) {
      const bf16* src = qkv + (krow + kr) * 3072 + kcol + ((ks ^ (kr & 7)) * 8);
      gload16(src, Ks + (tid >> 6) * 512);
    } else {
      const bf16* v0p = qkv + (krow + 2 * vp) * 3072 + vcol + vd0;
      uint64_t a = *(const uint64_t*)v0p;
      uint64_t b = *(const uint64_t*)(v0p + 3072);
#pragma unroll
      for (int e = 0; e < 4; ++e) {
        uint32_t w = (uint32_t)((a >> (16 * e)) & 0xFFFF) |
                     ((uint32_t)((b >> (16 * e)) & 0xFFFF) << 16);
        *(uint32_t*)(&Vt[0][0] + (vd0 + e) * 72 + 2 * vp) = w;
      }
    }
  }
  __syncthreads();

  for (int js = 0; js < nsel; ++js) {
    const int cur = js & 1;
    const int jblk = jof(js);
    const bool pre = (js + 1 < nsel);

    uint64_t va = 0, vb2 = 0;
    if (pre && !isK) {
      const bf16* v0p = qkv + ((size_t)jof(js + 1) * 64 + 2 * vp) * 3072 + vcol + vd0;
      va = *(const uint64_t*)v0p;
      vb2 = *(const uint64_t*)(v0p + 3072);
    }

    f32x4 s[4];
#pragma unroll
    for (int n = 0; n < 4; ++n) {
      const char* krowp = (const char*)Ks + (n * 16 + fr) * 128;
      bf16x8 kb0 = *(const bf16x8*)(krowp + ((g4 ^ (fr & 7)) << 4));
      bf16x8 kb1 = *(const bf16x8*)(krowp + (((4 + g4) ^ (fr & 7)) << 4));
      f32x4 z = {};
      z = mfma16(kb0, bq0, z);
      s[n] = mfma16(kb1, bq1, z);
    }

    __syncthreads();
    if (pre && isK) {
      const bf16* src = qkv + ((size_t)jof(js + 1) * 64 + kr) * 3072 + kcol +
                        ((ks ^ (kr & 7)) * 8);
      gload16(src, Ks + (tid >> 6) * 512);
    }

    const bool diag = (jblk == iblk);
    const int qr = rg * 16 + fr;
#pragma unroll
    for (int n = 0; n < 4; ++n)
#pragma unroll
      for (int i = 0; i < 4; ++i) {
        float sv = s[n][i] * ATT_SCALE;
        if (diag && (n * 16 + fr4 + i) > qr) sv = NEG_BIG;
        s[n][i] = sv;
      }

    float t0 = fmaxf(fmaxf(s[0][0], s[0][1]), fmaxf(s[0][2], s[0][3]));
    float t1 = fmaxf(fmaxf(s[1][0], s[1][1]), fmaxf(s[1][2], s[1][3]));
    float t2 = fmaxf(fmaxf(s[2][0], s[2][1]), fmaxf(s[2][2], s[2][3]));
    float t3 = fmaxf(fmaxf(s[3][0], s[3][1]), fmaxf(s[3][2], s[3][3]));
    float mx = fmaxf(fmaxf(t0, t1), fmaxf(t2, t3));
    mx = fmaxf(mx, __shfl_xor(mx, 16, 64));
    mx = fmaxf(mx, __shfl_xor(mx, 32, 64));
    float mnew = fmaxf(mrun, mx);
    float corr = __expf(mrun - mnew);
    mrun = mnew;
    float ps = 0.f;
#pragma unroll
    for (int n = 0; n < 4; ++n) {
      float p0 = __expf(s[n][0] - mnew), p1 = __expf(s[n][1] - mnew);
      float p2 = __expf(s[n][2] - mnew), p3 = __expf(s[n][3] - mnew);
      s[n][0] = p0; s[n][1] = p1; s[n][2] = p2; s[n][3] = p3;
      ps += (p0 + p1) + (p2 + p3);
    }
    ps += __shfl_xor(ps, 16, 64);
    ps += __shfl_xor(ps, 32, 64);
    lrun = lrun * corr + ps;

    float cq[4];
#pragma unroll
    for (int i = 0; i < 4; ++i) cq[i] = __shfl(corr, fr4 + i, 64);
#pragma unroll
    for (int n = 0; n < 4; ++n)
#pragma unroll
      for (int i = 0; i < 4; ++i) acc[n][i] *= cq[i];

    bf16* pbase = Ps + wid * (16 * 68);
#pragma unroll
    for (int n = 0; n < 4; ++n) {
      bf16x4 pk;
#pragma unroll
      for (int i = 0; i < 4; ++i) pk[i] = (bf16)s[n][i];
      *(bf16x4*)(pbase + fr * 68 + n * 16 + fr4) = pk;
    }
    bf16x8 pa0 = *(const bf16x8*)(pbase + fr * 68 + fk);
    bf16x8 pa1 = *(const bf16x8*)(pbase + fr * 68 + 32 + fk);

    if (pre && !isK) {
#pragma unroll
      for (int e = 0; e < 4; ++e) {
        uint32_t w = (uint32_t)((va >> (16 * e)) & 0xFFFF) |
                     ((uint32_t)((vb2 >> (16 * e)) & 0xFFFF) << 16);
        *(uint32_t*)(&Vt[cur ^ 1][0] + (vd0 + e) * 72 + 2 * vp) = w;
      }
    }

#pragma unroll
    for (int n = 0; n < 4; ++n) {
      bf16x8 vb0 = *(const bf16x8*)(&Vt[cur][0] + (n * 16 + fr) * 72 + fk);
      bf16x8 vb1 = *(const bf16x8*)(&Vt[cur][0] + (n * 16 + fr) * 72 + 32 + fk);
      acc[n] = mfma16(pa0, vb0, acc[n]);
      acc[n] = mfma16(pa1, vb1, acc[n]);
    }
    __syncthreads();
  }

  float lq[4];
#pragma unroll
  for (int i = 0; i < 4; ++i) lq[i] = __shfl(lrun, fr4 + i, 64);
#pragma unroll
  for (int i = 0; i < 4; ++i) {
    float rl = 1.0f / lq[i];
    size_t t = trow0 + rg * 16 + fr4 + i;
#pragma unroll
    for (int n = 0; n < 4; ++n)
      attn[t * 2048 + h * 64 + n * 16 + fr] = (bf16)(acc[n][i] * rl);
  }
}

// ---------------- launch ----------------
extern "C" void kernel_launch(void* const* d_in, const int* in_sizes, int n_in,
                              void* d_out, int out_size, void* d_ws, size_t ws_size,
                              hipStream_t stream) {
  (void)in_sizes; (void)n_in; (void)out_size; (void)ws_size;
  const float* hs = (const float*)d_in[0];
  const float* Wq = (const float*)d_in[1];
  const float* Wk = (const float*)d_in[2];
  const float* Wv = (const float*)d_in[3];
  const float* Wo = (const float*)d_in[4];
  float* out = (float*)d_out;

  char* ws = (char*)d_ws;
  bf16* hs16 = (bf16*)(ws + 0);              // 8192*2048*2  = 33554432
  bf16* qkv  = (bf16*)(ws + 33554432);       // 8192*3072*2  = 50331648
  bf16* attn = (bf16*)(ws + 83886080);       // 8192*2048*2  = 33554432
  bf16* wq16 = (bf16*)(ws + 117440512);      // 2048*2048*2  = 8388608
  bf16* wk16 = (bf16*)(ws + 125829120);      // 512*2048*2   = 2097152
  bf16* wv16 = (bf16*)(ws + 127926272);      // 512*2048*2   = 2097152
  bf16* wo16 = (bf16*)(ws + 130023424);      // 2048*2048*2  = 8388608
  float* cosT = (float*)(ws + 138412032);    // 8192*32*4    = 1048576
  float* sinT = (float*)(ws + 139460608);    // 8192*32*4    = 1048576

  prep_all<<<27648, 256, 0, stream>>>(hs, Wq, Wk, Wv, Wo,
                                      hs16, wq16, wk16, wv16, wo16, cosT, sinT);

  // QKV projection: M=8192, N=3072, K=2048, RoPE fused into epilogue
  gemm256<1, 0, 1><<<dim3(32, 12), 512, 0, stream>>>(hs16, wq16, wk16, wv16, qkv,
                                                     cosT, sinT, 3072, 2048);
  attn_sparse<<<dim3(128, 8), 1024, 0, stream>>>(qkv, attn);
  // O projection: M=8192, N=2048, K=2048, fp32 out
  gemm256<0, 1, 0><<<dim3(32, 8), 512, 0, stream>>>(attn, wo16, wo16, wo16, out,
                                                    nullptr, nullptr, 2048, 2048);
}

// Round 8
// 331.154 us; speedup vs baseline: 1.2851x; 1.2851x over previous
//
#include <hip/hip_runtime.h>
#include <cstdint>
#include <cstddef>

typedef __bf16 bf16;
typedef __attribute__((ext_vector_type(8))) __bf16 bf16x8;
typedef __attribute__((ext_vector_type(4))) __bf16 bf16x4;
typedef __attribute__((ext_vector_type(4))) float f32x4;

#define ATT_SCALE 0.125f   // 1/sqrt(64)
#define NEG_BIG  -1000000000.0f

__device__ __forceinline__ f32x4 mfma16(bf16x8 a, bf16x8 b, f32x4 c) {
  return __builtin_amdgcn_mfma_f32_16x16x32_bf16(a, b, c, 0, 0, 0);
}

__device__ __forceinline__ void gload16(const bf16* g, bf16* l) {
  __builtin_amdgcn_global_load_lds((__attribute__((address_space(1))) void*)g,
                                   (__attribute__((address_space(3))) void*)l,
                                   16, 0, 0);
}

// ---------------- fused prep: all fp32->bf16 converts + RoPE table ----------------
__global__ __launch_bounds__(256) void prep_all(const float* __restrict__ hs,
                                                const float* __restrict__ Wq,
                                                const float* __restrict__ Wk,
                                                const float* __restrict__ Wv,
                                                const float* __restrict__ Wo,
                                                bf16* __restrict__ hs16, bf16* __restrict__ wq16,
                                                bf16* __restrict__ wk16, bf16* __restrict__ wv16,
                                                bf16* __restrict__ wo16,
                                                float* __restrict__ cosT, float* __restrict__ sinT) {
  int b = blockIdx.x, t = threadIdx.x;
  const float* src; bf16* dst; int i;
  if (b < 16384)      { src = hs; dst = hs16; i = b * 256 + t; }
  else if (b < 20480) { src = Wq; dst = wq16; i = (b - 16384) * 256 + t; }
  else if (b < 21504) { src = Wk; dst = wk16; i = (b - 20480) * 256 + t; }
  else if (b < 22528) { src = Wv; dst = wv16; i = (b - 21504) * 256 + t; }
  else if (b < 26624) { src = Wo; dst = wo16; i = (b - 22528) * 256 + t; }
  else {
    int idx = (b - 26624) * 256 + t;   // 8192*32
    int tt = idx >> 5, j = idx & 31;
    float inv = exp2f(-(float)j * (13.287712379549449f / 32.0f));
    float fr = (float)tt * inv;
    cosT[idx] = cosf(fr); sinT[idx] = sinf(fr);
    return;
  }
  float4 v = *((const float4*)src + i);
  bf16x4 o;
  o[0] = (bf16)v.x; o[1] = (bf16)v.y; o[2] = (bf16)v.z; o[3] = (bf16)v.w;
  *((bf16x4*)dst + i) = o;
}

// ---------------- 256x256 bf16 GEMM, 2-tile sections (1 barrier / 2 K-tiles) ------
// C[m,n] = sum_k A[m,k]*B[n,k]. BK=32, 512 threads = 8 waves (2M x 4N),
// per-wave out 128x64 (acc[8][4]). LDS: 4-buffer rotation (A+B 32KB/buf) = 128 KB.
// Section s = tiles {2s, 2s+1}: ONE s_barrier at entry; mid-section is a bare
// vmcnt(4) (no barrier -> waves slip; tile 2s+1 ds_reads overlap tile 2s MFMA).
// Staging inside tile kt targets kt+2 -> section reads bufs {2s,2s+1} and writes
// {2s+2,2s+3}: disjoint mod 4, WAR-safe behind the entry barrier.
// vmcnt ledger (4 loads/tile, FIFO): entry vmcnt(4) -> stage(2s) landed;
// mid vmcnt(4) -> stage(2s+1) landed; last section: entry vmcnt(4), mid vmcnt(0).
// LDS chunk swizzle (0 conflicts, measured r4-r7): row r storage chunk p holds
// logical chunk p^((r>>1)&3); applied on GLOBAL source, LDS linear, reads same XOR.
// No XCD swizzle (r5 evidence: it destroys L2 A-panel locality at these grids).
template <int BSEL, int OUTF32, int ROPE>
__global__ __launch_bounds__(512, 2) void gemm256(const bf16* __restrict__ A,
                                                  const bf16* __restrict__ B0,
                                                  const bf16* __restrict__ B1,
                                                  const bf16* __restrict__ B2,
                                                  void* __restrict__ Cout,
                                                  const float* __restrict__ cosT,
                                                  const float* __restrict__ sinT,
                                                  int N, int K) {
  __shared__ bf16 As[4][8192];   // [buf][256 rows x 32 k]
  __shared__ bf16 Bs[4][8192];
  const int tid = threadIdx.x, lane = tid & 63, wid = tid >> 6;
  const int m0 = blockIdx.x * 256, n0 = blockIdx.y * 256;

  const int wr = wid >> 2, wc = wid & 3;      // wave row (0..1), col (0..3)
  const int fr = lane & 15, g4 = lane >> 4;
  const int sw8 = (g4 ^ ((fr >> 1) & 3)) * 8; // per-lane swizzled k-chunk offset (elems)

  f32x4 acc[8][4] = {};

  auto brow = [&](int n) -> const bf16* {
    if (BSEL) {
      if (n < 2048) return B0 + (size_t)n * K;
      if (n < 2560) return B1 + (size_t)(n - 2048) * K;
      return B2 + (size_t)(n - 2560) * K;
    }
    return B0 + (size_t)n * K;
  };

  // staging: per thread 2 chunks of A + 2 of B per K-tile. chunk c -> row c>>2,
  // logical col-chunk (c&3)^((r>>1)&3); LDS dest = c*16 bytes (linear).
  const bf16* aS0; const bf16* aS1; const bf16* bS0; const bf16* bS1;
  {
    int c0 = tid, r0 = c0 >> 2, l0 = (c0 & 3) ^ ((r0 >> 1) & 3);
    int c1 = 512 + tid, r1 = c1 >> 2, l1 = (c1 & 3) ^ ((r1 >> 1) & 3);
    aS0 = A + (size_t)(m0 + r0) * K + l0 * 8;
    aS1 = A + (size_t)(m0 + r1) * K + l1 * 8;
    bS0 = brow(n0 + r0) + l0 * 8;
    bS1 = brow(n0 + r1) + l1 * 8;
  }
  const int dst0 = (wid * 64) * 8;          // + HW lane*16B
  const int dst1 = (512 + wid * 64) * 8;

#define STAGE_A(KT) { bf16* d = &As[(KT) & 3][0]; \
    gload16(aS0 + (KT) * 32, d + dst0); gload16(aS1 + (KT) * 32, d + dst1); }
#define STAGE_B(KT) { bf16* d = &Bs[(KT) & 3][0]; \
    gload16(bS0 + (KT) * 32, d + dst0); gload16(bS1 + (KT) * 32, d + dst1); }

#define TILEBODY(KT, STG) { \
    const bf16* Ab = &As[(KT) & 3][0]; \
    const bf16* Bb = &Bs[(KT) & 3][0]; \
    bf16x8 bfr[4], af[4]; \
    _Pragma("unroll") for (int nf = 0; nf < 4; ++nf) \
      bfr[nf] = *(const bf16x8*)(Bb + (wc * 64 + nf * 16 + fr) * 32 + sw8); \
    _Pragma("unroll") for (int mf = 0; mf < 4; ++mf) \
      af[mf] = *(const bf16x8*)(Ab + (wr * 128 + mf * 16 + fr) * 32 + sw8); \
    if (STG) STAGE_A((KT) + 2); \
    __builtin_amdgcn_s_setprio(1); \
    _Pragma("unroll") for (int mf = 0; mf < 4; ++mf) \
      _Pragma("unroll") for (int nf = 0; nf < 4; ++nf) \
        acc[mf][nf] = mfma16(af[mf], bfr[nf], acc[mf][nf]); \
    __builtin_amdgcn_s_setprio(0); \
    _Pragma("unroll") for (int mf = 0; mf < 4; ++mf) \
      af[mf] = *(const bf16x8*)(Ab + (wr * 128 + 64 + mf * 16 + fr) * 32 + sw8); \
    if (STG) STAGE_B((KT) + 2); \
    __builtin_amdgcn_s_setprio(1); \
    _Pragma("unroll") for (int mf = 0; mf < 4; ++mf) \
      _Pragma("unroll") for (int nf = 0; nf < 4; ++nf) \
        acc[4 + mf][nf] = mfma16(af[mf], bfr[nf], acc[4 + mf][nf]); \
    __builtin_amdgcn_s_setprio(0); \
  }

  // prologue: stage tiles 0 and 1 (tile-0's 4 loads oldest in FIFO)
  STAGE_A(0); STAGE_B(0);
  STAGE_A(1); STAGE_B(1);

  const int NS = K >> 6;   // sections of 2 K-tiles; K=2048 -> 32
  for (int s = 0; s < NS - 1; ++s) {
    const int kt = 2 * s;
    asm volatile("s_waitcnt vmcnt(4)" ::: "memory");   // stage(kt) landed
    __builtin_amdgcn_s_barrier();
    __builtin_amdgcn_sched_barrier(0);
    TILEBODY(kt, 1)                                    // stages kt+2
    asm volatile("s_waitcnt vmcnt(4)" ::: "memory");   // stage(kt+1) landed (no barrier)
    TILEBODY(kt + 1, 1)                                // stages kt+3
  }
  { // final section: no staging; drain
    const int kt = 2 * (NS - 1);
    asm volatile("s_waitcnt vmcnt(4)" ::: "memory");
    __builtin_amdgcn_s_barrier();
    __builtin_amdgcn_sched_barrier(0);
    TILEBODY(kt, 0)
    asm volatile("s_waitcnt vmcnt(0)" ::: "memory");
    TILEBODY(kt + 1, 0)
  }
#undef TILEBODY
#undef STAGE_A
#undef STAGE_B

  // epilogue: acc[am] -> wave-tile row am*16 (am 0..3 first 64-row half, 4..7 second)
  const int fc = lane & 15, fr4 = (lane >> 4) * 4;
  if (ROPE && (n0 + wc * 64) < 2560) {
#pragma unroll
    for (int am = 0; am < 8; ++am)
#pragma unroll
      for (int i = 0; i < 4; ++i) {
        size_t row = (size_t)(m0 + wr * 128 + am * 16 + fr4 + i);
        bf16* base = (bf16*)Cout + row * (size_t)N + n0 + wc * 64;
#pragma unroll
        for (int nf = 0; nf < 2; ++nf) {
          int j = nf * 16 + fc;
          float c = cosT[row * 32 + j], sn = sinT[row * 32 + j];
          float x1 = acc[am][nf][i], x2 = acc[am][nf + 2][i];
          base[j]      = (bf16)(x1 * c - x2 * sn);
          base[j + 32] = (bf16)(x2 * c + x1 * sn);
        }
      }
  } else {
#pragma unroll
    for (int am = 0; am < 8; ++am)
#pragma unroll
      for (int i = 0; i < 4; ++i) {
        size_t row = (size_t)(m0 + wr * 128 + am * 16 + fr4 + i);
#pragma unroll
        for (int nf = 0; nf < 4; ++nf) {
          int col = n0 + wc * 64 + nf * 16 + fc;
          if (OUTF32)
            ((float*)Cout)[row * (size_t)N + col] = acc[am][nf][i];
          else
            ((bf16*)Cout)[row * (size_t)N + col] = (bf16)acc[am][nf][i];
        }
      }
  }
}

// ---------------- block-sparse attention, GQA-grouped, pipelined ----------------
// (unchanged — validated)
__global__ __launch_bounds__(1024) void attn_sparse(const bf16* __restrict__ qkv,
                                                    bf16* __restrict__ attn) {
  const int iblk = blockIdx.x;
  const int kv = blockIdx.y;
  const int tid = threadIdx.x, lane = tid & 63, wid = tid >> 6;
  const int hloc = wid >> 2;
  const int h = kv * 4 + hloc;
  const int rg = wid & 3;

  __shared__ bf16 Ks[64 * 64];
  __shared__ bf16 Vt[2][64 * 72];
  __shared__ bf16 Ps[16 * 16 * 68];

  const int qcol = h * 64, kcol = 2048 + kv * 64, vcol = 2560 + kv * 64;
  const size_t trow0 = (size_t)iblk * 64;
  const int fr = lane & 15, g4 = lane >> 4, fk = g4 * 8, fr4 = g4 * 4;

  const bf16* qrow = qkv + (trow0 + rg * 16 + fr) * 3072 + qcol;
  bf16x8 bq0 = *(const bf16x8*)(qrow + fk);
  bf16x8 bq1 = *(const bf16x8*)(qrow + 32 + fk);

  float mrun = -INFINITY, lrun = 0.f;
  f32x4 acc[4] = {};

  const int kr = tid >> 3, ks = tid & 7;
  const int vu = tid & 511, vp = vu & 31, vd0 = (vu >> 5) * 4;
  const bool isK = (tid < 512);

  const int nsel = (iblk < 8) ? (iblk + 1) : 9;
  auto jof = [&](int js) { return (iblk < 8) ? js : ((js == 0) ? 0 : iblk - 8 + js); };

  {
    const size_t krow = (size_t)jof(0) * 64;
    if (isK) {
      const bf16* src = qkv + (krow + kr) * 3072 + kcol + ((ks ^ (kr & 7)) * 8);
      gload16(src, Ks + (tid >> 6) * 512);
    } else {
      const bf16* v0p = qkv + (krow + 2 * vp) * 3072 + vcol + vd0;
      uint64_t a = *(const uint64_t*)v0p;
      uint64_t b = *(const uint64_t*)(v0p + 3072);
#pragma unroll
      for (int e = 0; e < 4; ++e) {
        uint32_t w = (uint32_t)((a >> (16 * e)) & 0xFFFF) |
                     ((uint32_t)((b >> (16 * e)) & 0xFFFF) << 16);
        *(uint32_t*)(&Vt[0][0] + (vd0 + e) * 72 + 2 * vp) = w;
      }
    }
  }
  __syncthreads();

  for (int js = 0; js < nsel; ++js) {
    const int cur = js & 1;
    const int jblk = jof(js);
    const bool pre = (js + 1 < nsel);

    uint64_t va = 0, vb2 = 0;
    if (pre && !isK) {
      const bf16* v0p = qkv + ((size_t)jof(js + 1) * 64 + 2 * vp) * 3072 + vcol + vd0;
      va = *(const uint64_t*)v0p;
      vb2 = *(const uint64_t*)(v0p + 3072);
    }

    f32x4 s[4];
#pragma unroll
    for (int n = 0; n < 4; ++n) {
      const char* krowp = (const char*)Ks + (n * 16 + fr) * 128;
      bf16x8 kb0 = *(const bf16x8*)(krowp + ((g4 ^ (fr & 7)) << 4));
      bf16x8 kb1 = *(const bf16x8*)(krowp + (((4 + g4) ^ (fr & 7)) << 4));
      f32x4 z = {};
      z = mfma16(kb0, bq0, z);
      s[n] = mfma16(kb1, bq1, z);
    }

    __syncthreads();
    if (pre && isK) {
      const bf16* src = qkv + ((size_t)jof(js + 1) * 64 + kr) * 3072 + kcol +
                        ((ks ^ (kr & 7)) * 8);
      gload16(src, Ks + (tid >> 6) * 512);
    }

    const bool diag = (jblk == iblk);
    const int qr = rg * 16 + fr;
#pragma unroll
    for (int n = 0; n < 4; ++n)
#pragma unroll
      for (int i = 0; i < 4; ++i) {
        float sv = s[n][i] * ATT_SCALE;
        if (diag && (n * 16 + fr4 + i) > qr) sv = NEG_BIG;
        s[n][i] = sv;
      }

    float t0 = fmaxf(fmaxf(s[0][0], s[0][1]), fmaxf(s[0][2], s[0][3]));
    float t1 = fmaxf(fmaxf(s[1][0], s[1][1]), fmaxf(s[1][2], s[1][3]));
    float t2 = fmaxf(fmaxf(s[2][0], s[2][1]), fmaxf(s[2][2], s[2][3]));
    float t3 = fmaxf(fmaxf(s[3][0], s[3][1]), fmaxf(s[3][2], s[3][3]));
    float mx = fmaxf(fmaxf(t0, t1), fmaxf(t2, t3));
    mx = fmaxf(mx, __shfl_xor(mx, 16, 64));
    mx = fmaxf(mx, __shfl_xor(mx, 32, 64));
    float mnew = fmaxf(mrun, mx);
    float corr = __expf(mrun - mnew);
    mrun = mnew;
    float ps = 0.f;
#pragma unroll
    for (int n = 0; n < 4; ++n) {
      float p0 = __expf(s[n][0] - mnew), p1 = __expf(s[n][1] - mnew);
      float p2 = __expf(s[n][2] - mnew), p3 = __expf(s[n][3] - mnew);
      s[n][0] = p0; s[n][1] = p1; s[n][2] = p2; s[n][3] = p3;
      ps += (p0 + p1) + (p2 + p3);
    }
    ps += __shfl_xor(ps, 16, 64);
    ps += __shfl_xor(ps, 32, 64);
    lrun = lrun * corr + ps;

    float cq[4];
#pragma unroll
    for (int i = 0; i < 4; ++i) cq[i] = __shfl(corr, fr4 + i, 64);
#pragma unroll
    for (int n = 0; n < 4; ++n)
#pragma unroll
      for (int i = 0; i < 4; ++i) acc[n][i] *= cq[i];

    bf16* pbase = Ps + wid * (16 * 68);
#pragma unroll
    for (int n = 0; n < 4; ++n) {
      bf16x4 pk;
#pragma unroll
      for (int i = 0; i < 4; ++i) pk[i] = (bf16)s[n][i];
      *(bf16x4*)(pbase + fr * 68 + n * 16 + fr4) = pk;
    }
    bf16x8 pa0 = *(const bf16x8*)(pbase + fr * 68 + fk);
    bf16x8 pa1 = *(const bf16x8*)(pbase + fr * 68 + 32 + fk);

    if (pre && !isK) {
#pragma unroll
      for (int e = 0; e < 4; ++e) {
        uint32_t w = (uint32_t)((va >> (16 * e)) & 0xFFFF) |
                     ((uint32_t)((vb2 >> (16 * e)) & 0xFFFF) << 16);
        *(uint32_t*)(&Vt[cur ^ 1][0] + (vd0 + e) * 72 + 2 * vp) = w;
      }
    }

#pragma unroll
    for (int n = 0; n < 4; ++n) {
      bf16x8 vb0 = *(const bf16x8*)(&Vt[cur][0] + (n * 16 + fr) * 72 + fk);
      bf16x8 vb1 = *(const bf16x8*)(&Vt[cur][0] + (n * 16 + fr) * 72 + 32 + fk);
      acc[n] = mfma16(pa0, vb0, acc[n]);
      acc[n] = mfma16(pa1, vb1, acc[n]);
    }
    __syncthreads();
  }

  float lq[4];
#pragma unroll
  for (int i = 0; i < 4; ++i) lq[i] = __shfl(lrun, fr4 + i, 64);
#pragma unroll
  for (int i = 0; i < 4; ++i) {
    float rl = 1.0f / lq[i];
    size_t t = trow0 + rg * 16 + fr4 + i;
#pragma unroll
    for (int n = 0; n < 4; ++n)
      attn[t * 2048 + h * 64 + n * 16 + fr] = (bf16)(acc[n][i] * rl);
  }
}

// ---------------- launch ----------------
extern "C" void kernel_launch(void* const* d_in, const int* in_sizes, int n_in,
                              void* d_out, int out_size, void* d_ws, size_t ws_size,
                              hipStream_t stream) {
  (void)in_sizes; (void)n_in; (void)out_size; (void)ws_size;
  const float* hs = (const float*)d_in[0];
  const float* Wq = (const float*)d_in[1];
  const float* Wk = (const float*)d_in[2];
  const float* Wv = (const float*)d_in[3];
  const float* Wo = (const float*)d_in[4];
  float* out = (float*)d_out;

  char* ws = (char*)d_ws;
  bf16* hs16 = (bf16*)(ws + 0);              // 8192*2048*2  = 33554432
  bf16* qkv  = (bf16*)(ws + 33554432);       // 8192*3072*2  = 50331648
  bf16* attn = (bf16*)(ws + 83886080);       // 8192*2048*2  = 33554432
  bf16* wq16 = (bf16*)(ws + 117440512);      // 2048*2048*2  = 8388608
  bf16* wk16 = (bf16*)(ws + 125829120);      // 512*2048*2   = 2097152
  bf16* wv16 = (bf16*)(ws + 127926272);      // 512*2048*2   = 2097152
  bf16* wo16 = (bf16*)(ws + 130023424);      // 2048*2048*2  = 8388608
  float* cosT = (float*)(ws + 138412032);    // 8192*32*4    = 1048576
  float* sinT = (float*)(ws + 139460608);    // 8192*32*4    = 1048576

  prep_all<<<27648, 256, 0, stream>>>(hs, Wq, Wk, Wv, Wo,
                                      hs16, wq16, wk16, wv16, wo16, cosT, sinT);

  // QKV projection: M=8192, N=3072, K=2048, RoPE fused into epilogue
  gemm256<1, 0, 1><<<dim3(32, 12), 512, 0, stream>>>(hs16, wq16, wk16, wv16, qkv,
                                                     cosT, sinT, 3072, 2048);
  attn_sparse<<<dim3(128, 8), 1024, 0, stream>>>(qkv, attn);
  // O projection: M=8192, N=2048, K=2048, fp32 out
  gemm256<0, 1, 0><<<dim3(32, 8), 512, 0, stream>>>(attn, wo16, wo16, wo16, out,
                                                    nullptr, nullptr, 2048, 2048);
}

// Round 9
// 299.553 us; speedup vs baseline: 1.4206x; 1.1055x over previous
//
#include <hip/hip_runtime.h>
#include <cstdint>
#include <cstddef>

typedef __bf16 bf16;
typedef __attribute__((ext_vector_type(8))) __bf16 bf16x8;
typedef __attribute__((ext_vector_type(4))) __bf16 bf16x4;
typedef __attribute__((ext_vector_type(4))) float f32x4;

#define ATT_SCALE 0.125f   // 1/sqrt(64)
#define NEG_BIG  -1000000000.0f

__device__ __forceinline__ f32x4 mfma16(bf16x8 a, bf16x8 b, f32x4 c) {
  return __builtin_amdgcn_mfma_f32_16x16x32_bf16(a, b, c, 0, 0, 0);
}

__device__ __forceinline__ void gload16(const bf16* g, bf16* l) {
  __builtin_amdgcn_global_load_lds((__attribute__((address_space(1))) void*)g,
                                   (__attribute__((address_space(3))) void*)l,
                                   16, 0, 0);
}

// ---------------- fused prep: all fp32->bf16 converts + RoPE table ----------------
__global__ __launch_bounds__(256) void prep_all(const float* __restrict__ hs,
                                                const float* __restrict__ Wq,
                                                const float* __restrict__ Wk,
                                                const float* __restrict__ Wv,
                                                const float* __restrict__ Wo,
                                                bf16* __restrict__ hs16, bf16* __restrict__ wq16,
                                                bf16* __restrict__ wk16, bf16* __restrict__ wv16,
                                                bf16* __restrict__ wo16,
                                                float* __restrict__ cosT, float* __restrict__ sinT) {
  int b = blockIdx.x, t = threadIdx.x;
  const float* src; bf16* dst; int i;
  if (b < 16384)      { src = hs; dst = hs16; i = b * 256 + t; }
  else if (b < 20480) { src = Wq; dst = wq16; i = (b - 16384) * 256 + t; }
  else if (b < 21504) { src = Wk; dst = wk16; i = (b - 20480) * 256 + t; }
  else if (b < 22528) { src = Wv; dst = wv16; i = (b - 21504) * 256 + t; }
  else if (b < 26624) { src = Wo; dst = wo16; i = (b - 22528) * 256 + t; }
  else {
    int idx = (b - 26624) * 256 + t;   // 8192*32
    int tt = idx >> 5, j = idx & 31;
    float inv = exp2f(-(float)j * (13.287712379549449f / 32.0f));
    float fr = (float)tt * inv;
    cosT[idx] = cosf(fr); sinT[idx] = sinf(fr);
    return;
  }
  float4 v = *((const float4*)src + i);
  bf16x4 o;
  o[0] = (bf16)v.x; o[1] = (bf16)v.y; o[2] = (bf16)v.z; o[3] = (bf16)v.w;
  *((bf16x4*)dst + i) = o;
}

// ---------------- QKV GEMM: 256x384 tile, grid (32,8)=256 blocks (zero tail) ------
// C[m,n] = sum_k A[m,k]*B[n,k]; M=8192 N=3072 K=2048, BK=32.
// 512 threads = 8 waves as 4M x 2N -> per-wave 64 rows x 192 cols (3 heads, RoPE-
// aligned). acc[4][12]. LDS: 3-buffer rotation, A 16KB + B 24KB per buf = 120 KB.
// Per-CU LDS read per K-tile: A dup2 + B dup4 = 112KB per 6.3 MFLOP (vs 96/4.2 at
// 256^2) — less LDS per FLOP AND zero dispatch tail.
// Staging: uniform 5 gload_lds per thread per tile (A:2, B:3); ledger: prologue
// stages tiles 0,1 (10); tile kt entry waits vmcnt(5) -> kt landed; body stages
// kt+2 (WAR-safe: buf (kt+2)%3 last read by tile kt-1, done before entry barrier).
// Tail: tile 62 entry vmcnt(5) no stage; tile 63 vmcnt(0).
// Chunk swizzle (0 conflicts r4-r8): row r chunk p holds logical p^((r>>1)&3);
// swizzle on GLOBAL source, LDS linear, reads same XOR.
__global__ __launch_bounds__(512) void gemm_qkv(const bf16* __restrict__ A,
                                                const bf16* __restrict__ B0,
                                                const bf16* __restrict__ B1,
                                                const bf16* __restrict__ B2,
                                                bf16* __restrict__ C,
                                                const float* __restrict__ cosT,
                                                const float* __restrict__ sinT) {
  __shared__ bf16 As[3][8192];    // 16 KB per buf
  __shared__ bf16 Bs[3][12288];   // 24 KB per buf
  const int tid = threadIdx.x, lane = tid & 63, wid = tid >> 6;
  const int m0 = blockIdx.x * 256, n0 = blockIdx.y * 384;
  const int wr = wid >> 1, wc = wid & 1;
  const int fr = lane & 15, g4 = lane >> 4;
  const int sw8 = (g4 ^ ((fr >> 1) & 3)) * 8;

  f32x4 acc[4][12] = {};

  auto brow = [&](int n) -> const bf16* {
    if (n < 2048) return B0 + (size_t)n * 2048;
    if (n < 2560) return B1 + (size_t)(n - 2048) * 2048;
    return B2 + (size_t)(n - 2560) * 2048;
  };

  const int ra0 = tid >> 2, ra1 = 128 + (tid >> 2), rb2r = 256 + (tid >> 2);
  const bf16* aS0 = A + (size_t)(m0 + ra0) * 2048 + ((tid & 3) ^ ((ra0 >> 1) & 3)) * 8;
  const bf16* aS1 = A + (size_t)(m0 + ra1) * 2048 + ((tid & 3) ^ ((ra1 >> 1) & 3)) * 8;
  const bf16* bS0 = brow(n0 + ra0) + ((tid & 3) ^ ((ra0 >> 1) & 3)) * 8;
  const bf16* bS1 = brow(n0 + ra1) + ((tid & 3) ^ ((ra1 >> 1) & 3)) * 8;
  const bf16* bS2 = brow(n0 + rb2r) + ((tid & 3) ^ ((rb2r >> 1) & 3)) * 8;
  const int d0 = wid * 512, d1 = 4096 + wid * 512, d2 = 8192 + wid * 512;

#define STQA(BS, KT)  { bf16* d = &As[BS][0]; \
    gload16(aS0 + (KT) * 32, d + d0); gload16(aS1 + (KT) * 32, d + d1); }
#define STQB0(BS, KT) { bf16* d = &Bs[BS][0]; \
    gload16(bS0 + (KT) * 32, d + d0); gload16(bS1 + (KT) * 32, d + d1); }
#define STQB1(BS, KT) { gload16(bS2 + (KT) * 32, &Bs[BS][0] + d2); }

#define QTILE(KT, BI, BS, VM, STG) { \
    asm volatile("s_waitcnt vmcnt(" VM ")" ::: "memory"); \
    __builtin_amdgcn_s_barrier(); \
    __builtin_amdgcn_sched_barrier(0); \
    const bf16* Ab = &As[BI][0]; \
    const bf16* Bb = &Bs[BI][0]; \
    bf16x8 af[4], bfr[4]; \
    _Pragma("unroll") for (int mf = 0; mf < 4; ++mf) \
      af[mf] = *(const bf16x8*)(Ab + (wr * 64 + mf * 16 + fr) * 32 + sw8); \
    _Pragma("unroll") for (int q = 0; q < 4; ++q) \
      bfr[q] = *(const bf16x8*)(Bb + (wc * 192 + q * 16 + fr) * 32 + sw8); \
    if (STG) STQA(BS, (KT) + 2); \
    __builtin_amdgcn_s_setprio(1); \
    _Pragma("unroll") for (int mf = 0; mf < 4; ++mf) \
      _Pragma("unroll") for (int q = 0; q < 4; ++q) \
        acc[mf][q] = mfma16(af[mf], bfr[q], acc[mf][q]); \
    __builtin_amdgcn_s_setprio(0); \
    _Pragma("unroll") for (int q = 0; q < 4; ++q) \
      bfr[q] = *(const bf16x8*)(Bb + (wc * 192 + 64 + q * 16 + fr) * 32 + sw8); \
    if (STG) STQB0(BS, (KT) + 2); \
    __builtin_amdgcn_s_setprio(1); \
    _Pragma("unroll") for (int mf = 0; mf < 4; ++mf) \
      _Pragma("unroll") for (int q = 0; q < 4; ++q) \
        acc[mf][4 + q] = mfma16(af[mf], bfr[q], acc[mf][4 + q]); \
    __builtin_amdgcn_s_setprio(0); \
    _Pragma("unroll") for (int q = 0; q < 4; ++q) \
      bfr[q] = *(const bf16x8*)(Bb + (wc * 192 + 128 + q * 16 + fr) * 32 + sw8); \
    if (STG) STQB1(BS, (KT) + 2); \
    __builtin_amdgcn_s_setprio(1); \
    _Pragma("unroll") for (int mf = 0; mf < 4; ++mf) \
      _Pragma("unroll") for (int q = 0; q < 4; ++q) \
        acc[mf][8 + q] = mfma16(af[mf], bfr[q], acc[mf][8 + q]); \
    __builtin_amdgcn_s_setprio(0); \
  }

  // prologue: stage tiles 0 (buf0) and 1 (buf1): 10 loads in flight
  STQA(0, 0); STQB0(0, 0); STQB1(0, 0);
  STQA(1, 1); STQB0(1, 1); STQB1(1, 1);

  int bi = 0, bs = 2;
  for (int kt = 0; kt < 62; ++kt) {
    QTILE(kt, bi, bs, "5", 1)
    bi = (bi == 2) ? 0 : bi + 1;
    bs = (bs == 2) ? 0 : bs + 1;
  }
  QTILE(62, bi, bs, "5", 0)
  bi = (bi == 2) ? 0 : bi + 1;
  QTILE(63, bi, bi, "0", 0)
#undef QTILE
#undef STQA
#undef STQB0
#undef STQB1

  // epilogue: rows m0+wr*64+mf*16+fr4+i; cols n0+wc*192+g*64+{j,j+32} (RoPE) per head
  const int fc = lane & 15, fr4 = (lane >> 4) * 4;
#pragma unroll
  for (int mf = 0; mf < 4; ++mf)
#pragma unroll
    for (int i = 0; i < 4; ++i) {
      size_t row = (size_t)(m0 + wr * 64 + mf * 16 + fr4 + i);
      bf16* base = C + row * 3072 + n0 + wc * 192;
      const float* cr = cosT + row * 32;
      const float* sr = sinT + row * 32;
#pragma unroll
      for (int g = 0; g < 3; ++g) {
        if (n0 + wc * 192 + g * 64 < 2560) {
#pragma unroll
          for (int q = 0; q < 2; ++q) {
            int j = q * 16 + fc;
            float c = cr[j], sn = sr[j];
            float x1 = acc[mf][g * 4 + q][i], x2 = acc[mf][g * 4 + q + 2][i];
            base[g * 64 + j]      = (bf16)(x1 * c - x2 * sn);
            base[g * 64 + j + 32] = (bf16)(x2 * c + x1 * sn);
          }
        } else {
#pragma unroll
          for (int q = 0; q < 4; ++q)
            base[g * 64 + q * 16 + fc] = (bf16)acc[mf][g * 4 + q][i];
        }
      }
    }
}

// ---------------- O-proj GEMM: r4-best 256x256, 4-buf, 1 barrier/K-tile ----------
// (verbatim r4 structure; fp32 out; grid (32,8)=256 = exactly 1 round)
__global__ __launch_bounds__(512, 2) void gemm_out(const bf16* __restrict__ A,
                                                   const bf16* __restrict__ B0,
                                                   float* __restrict__ Cout) {
  __shared__ bf16 As[4][8192];
  __shared__ bf16 Bs[4][8192];
  const int tid = threadIdx.x, lane = tid & 63, wid = tid >> 6;
  const int m0 = blockIdx.x * 256, n0 = blockIdx.y * 256;
  const int wr = wid >> 2, wc = wid & 3;
  const int fr = lane & 15, g4 = lane >> 4;
  const int sw8 = (g4 ^ ((fr >> 1) & 3)) * 8;
  const int K = 2048, N = 2048;

  f32x4 acc[8][4] = {};

  const bf16* aS0; const bf16* aS1; const bf16* bS0; const bf16* bS1;
  {
    int c0 = tid, r0 = c0 >> 2, l0 = (c0 & 3) ^ ((r0 >> 1) & 3);
    int c1 = 512 + tid, r1 = c1 >> 2, l1 = (c1 & 3) ^ ((r1 >> 1) & 3);
    aS0 = A + (size_t)(m0 + r0) * K + l0 * 8;
    aS1 = A + (size_t)(m0 + r1) * K + l1 * 8;
    bS0 = B0 + (size_t)(n0 + r0) * K + l0 * 8;
    bS1 = B0 + (size_t)(n0 + r1) * K + l1 * 8;
  }
  const int dst0 = wid * 512;
  const int dst1 = 4096 + wid * 512;

#define STAGE_A(KT) { bf16* d = &As[(KT) & 3][0]; \
    gload16(aS0 + (KT) * 32, d + dst0); gload16(aS1 + (KT) * 32, d + dst1); }
#define STAGE_B(KT) { bf16* d = &Bs[(KT) & 3][0]; \
    gload16(bS0 + (KT) * 32, d + dst0); gload16(bS1 + (KT) * 32, d + dst1); }

#define KTILE(KT, VM, STG) { \
    asm volatile("s_waitcnt vmcnt(" VM ")" ::: "memory"); \
    __builtin_amdgcn_s_barrier(); \
    __builtin_amdgcn_sched_barrier(0); \
    const bf16* Ab = &As[(KT) & 3][0]; \
    const bf16* Bb = &Bs[(KT) & 3][0]; \
    bf16x8 bfr[4], af[4]; \
    _Pragma("unroll") for (int nf = 0; nf < 4; ++nf) \
      bfr[nf] = *(const bf16x8*)(Bb + (wc * 64 + nf * 16 + fr) * 32 + sw8); \
    _Pragma("unroll") for (int mf = 0; mf < 4; ++mf) \
      af[mf] = *(const bf16x8*)(Ab + (wr * 128 + mf * 16 + fr) * 32 + sw8); \
    if (STG) STAGE_A((KT) + 3); \
    __builtin_amdgcn_s_setprio(1); \
    _Pragma("unroll") for (int mf = 0; mf < 4; ++mf) \
      _Pragma("unroll") for (int nf = 0; nf < 4; ++nf) \
        acc[mf][nf] = mfma16(af[mf], bfr[nf], acc[mf][nf]); \
    __builtin_amdgcn_s_setprio(0); \
    _Pragma("unroll") for (int mf = 0; mf < 4; ++mf) \
      af[mf] = *(const bf16x8*)(Ab + (wr * 128 + 64 + mf * 16 + fr) * 32 + sw8); \
    if (STG) STAGE_B((KT) + 3); \
    __builtin_amdgcn_s_setprio(1); \
    _Pragma("unroll") for (int mf = 0; mf < 4; ++mf) \
      _Pragma("unroll") for (int nf = 0; nf < 4; ++nf) \
        acc[4 + mf][nf] = mfma16(af[mf], bfr[nf], acc[4 + mf][nf]); \
    __builtin_amdgcn_s_setprio(0); \
  }

  STAGE_A(0); STAGE_B(0);
  STAGE_A(1); STAGE_B(1);
  STAGE_A(2); STAGE_B(2);

  const int NT = K >> 5;   // 64
  for (int kt = 0; kt < NT - 3; ++kt) KTILE(kt, "8", 1)
  KTILE(NT - 3, "8", 0)
  KTILE(NT - 2, "4", 0)
  KTILE(NT - 1, "0", 0)
#undef KTILE
#undef STAGE_A
#undef STAGE_B

  const int fc = lane & 15, fr4 = (lane >> 4) * 4;
#pragma unroll
  for (int am = 0; am < 8; ++am)
#pragma unroll
    for (int i = 0; i < 4; ++i) {
      size_t row = (size_t)(m0 + wr * 128 + am * 16 + fr4 + i);
#pragma unroll
      for (int nf = 0; nf < 4; ++nf) {
        int col = n0 + wc * 64 + nf * 16 + fc;
        Cout[row * (size_t)N + col] = acc[am][nf][i];
      }
    }
}

// ---------------- block-sparse attention, GQA-grouped, pipelined ----------------
// (unchanged — validated)
__global__ __launch_bounds__(1024) void attn_sparse(const bf16* __restrict__ qkv,
                                                    bf16* __restrict__ attn) {
  const int iblk = blockIdx.x;
  const int kv = blockIdx.y;
  const int tid = threadIdx.x, lane = tid & 63, wid = tid >> 6;
  const int hloc = wid >> 2;
  const int h = kv * 4 + hloc;
  const int rg = wid & 3;

  __shared__ bf16 Ks[64 * 64];
  __shared__ bf16 Vt[2][64 * 72];
  __shared__ bf16 Ps[16 * 16 * 68];

  const int qcol = h * 64, kcol = 2048 + kv * 64, vcol = 2560 + kv * 64;
  const size_t trow0 = (size_t)iblk * 64;
  const int fr = lane & 15, g4 = lane >> 4, fk = g4 * 8, fr4 = g4 * 4;

  const bf16* qrow = qkv + (trow0 + rg * 16 + fr) * 3072 + qcol;
  bf16x8 bq0 = *(const bf16x8*)(qrow + fk);
  bf16x8 bq1 = *(const bf16x8*)(qrow + 32 + fk);

  float mrun = -INFINITY, lrun = 0.f;
  f32x4 acc[4] = {};

  const int kr = tid >> 3, ks = tid & 7;
  const int vu = tid & 511, vp = vu & 31, vd0 = (vu >> 5) * 4;
  const bool isK = (tid < 512);

  const int nsel = (iblk < 8) ? (iblk + 1) : 9;
  auto jof = [&](int js) { return (iblk < 8) ? js : ((js == 0) ? 0 : iblk - 8 + js); };

  {
    const size_t krow = (size_t)jof(0) * 64;
    if (isK) {
      const bf16* src = qkv + (krow + kr) * 3072 + kcol + ((ks ^ (kr & 7)) * 8);
      gload16(src, Ks + (tid >> 6) * 512);
    } else {
      const bf16* v0p = qkv + (krow + 2 * vp) * 3072 + vcol + vd0;
      uint64_t a = *(const uint64_t*)v0p;
      uint64_t b = *(const uint64_t*)(v0p + 3072);
#pragma unroll
      for (int e = 0; e < 4; ++e) {
        uint32_t w = (uint32_t)((a >> (16 * e)) & 0xFFFF) |
                     ((uint32_t)((b >> (16 * e)) & 0xFFFF) << 16);
        *(uint32_t*)(&Vt[0][0] + (vd0 + e) * 72 + 2 * vp) = w;
      }
    }
  }
  __syncthreads();

  for (int js = 0; js < nsel; ++js) {
    const int cur = js & 1;
    const int jblk = jof(js);
    const bool pre = (js + 1 < nsel);

    uint64_t va = 0, vb2 = 0;
    if (pre && !isK) {
      const bf16* v0p = qkv + ((size_t)jof(js + 1) * 64 + 2 * vp) * 3072 + vcol + vd0;
      va = *(const uint64_t*)v0p;
      vb2 = *(const uint64_t*)(v0p + 3072);
    }

    f32x4 s[4];
#pragma unroll
    for (int n = 0; n < 4; ++n) {
      const char* krowp = (const char*)Ks + (n * 16 + fr) * 128;
      bf16x8 kb0 = *(const bf16x8*)(krowp + ((g4 ^ (fr & 7)) << 4));
      bf16x8 kb1 = *(const bf16x8*)(krowp + (((4 + g4) ^ (fr & 7)) << 4));
      f32x4 z = {};
      z = mfma16(kb0, bq0, z);
      s[n] = mfma16(kb1, bq1, z);
    }

    __syncthreads();
    if (pre && isK) {
      const bf16* src = qkv + ((size_t)jof(js + 1) * 64 + kr) * 3072 + kcol +
                        ((ks ^ (kr & 7)) * 8);
      gload16(src, Ks + (tid >> 6) * 512);
    }

    const bool diag = (jblk == iblk);
    const int qr = rg * 16 + fr;
#pragma unroll
    for (int n = 0; n < 4; ++n)
#pragma unroll
      for (int i = 0; i < 4; ++i) {
        float sv = s[n][i] * ATT_SCALE;
        if (diag && (n * 16 + fr4 + i) > qr) sv = NEG_BIG;
        s[n][i] = sv;
      }

    float t0 = fmaxf(fmaxf(s[0][0], s[0][1]), fmaxf(s[0][2], s[0][3]));
    float t1 = fmaxf(fmaxf(s[1][0], s[1][1]), fmaxf(s[1][2], s[1][3]));
    float t2 = fmaxf(fmaxf(s[2][0], s[2][1]), fmaxf(s[2][2], s[2][3]));
    float t3 = fmaxf(fmaxf(s[3][0], s[3][1]), fmaxf(s[3][2], s[3][3]));
    float mx = fmaxf(fmaxf(t0, t1), fmaxf(t2, t3));
    mx = fmaxf(mx, __shfl_xor(mx, 16, 64));
    mx = fmaxf(mx, __shfl_xor(mx, 32, 64));
    float mnew = fmaxf(mrun, mx);
    float corr = __expf(mrun - mnew);
    mrun = mnew;
    float ps = 0.f;
#pragma unroll
    for (int n = 0; n < 4; ++n) {
      float p0 = __expf(s[n][0] - mnew), p1 = __expf(s[n][1] - mnew);
      float p2 = __expf(s[n][2] - mnew), p3 = __expf(s[n][3] - mnew);
      s[n][0] = p0; s[n][1] = p1; s[n][2] = p2; s[n][3] = p3;
      ps += (p0 + p1) + (p2 + p3);
    }
    ps += __shfl_xor(ps, 16, 64);
    ps += __shfl_xor(ps, 32, 64);
    lrun = lrun * corr + ps;

    float cq[4];
#pragma unroll
    for (int i = 0; i < 4; ++i) cq[i] = __shfl(corr, fr4 + i, 64);
#pragma unroll
    for (int n = 0; n < 4; ++n)
#pragma unroll
      for (int i = 0; i < 4; ++i) acc[n][i] *= cq[i];

    bf16* pbase = Ps + wid * (16 * 68);
#pragma unroll
    for (int n = 0; n < 4; ++n) {
      bf16x4 pk;
#pragma unroll
      for (int i = 0; i < 4; ++i) pk[i] = (bf16)s[n][i];
      *(bf16x4*)(pbase + fr * 68 + n * 16 + fr4) = pk;
    }
    bf16x8 pa0 = *(const bf16x8*)(pbase + fr * 68 + fk);
    bf16x8 pa1 = *(const bf16x8*)(pbase + fr * 68 + 32 + fk);

    if (pre && !isK) {
#pragma unroll
      for (int e = 0; e < 4; ++e) {
        uint32_t w = (uint32_t)((va >> (16 * e)) & 0xFFFF) |
                     ((uint32_t)((vb2 >> (16 * e)) & 0xFFFF) << 16);
        *(uint32_t*)(&Vt[cur ^ 1][0] + (vd0 + e) * 72 + 2 * vp) = w;
      }
    }

#pragma unroll
    for (int n = 0; n < 4; ++n) {
      bf16x8 vb0 = *(const bf16x8*)(&Vt[cur][0] + (n * 16 + fr) * 72 + fk);
      bf16x8 vb1 = *(const bf16x8*)(&Vt[cur][0] + (n * 16 + fr) * 72 + 32 + fk);
      acc[n] = mfma16(pa0, vb0, acc[n]);
      acc[n] = mfma16(pa1, vb1, acc[n]);
    }
    __syncthreads();
  }

  float lq[4];
#pragma unroll
  for (int i = 0; i < 4; ++i) lq[i] = __shfl(lrun, fr4 + i, 64);
#pragma unroll
  for (int i = 0; i < 4; ++i) {
    float rl = 1.0f / lq[i];
    size_t t = trow0 + rg * 16 + fr4 + i;
#pragma unroll
    for (int n = 0; n < 4; ++n)
      attn[t * 2048 + h * 64 + n * 16 + fr] = (bf16)(acc[n][i] * rl);
  }
}

// ---------------- launch ----------------
extern "C" void kernel_launch(void* const* d_in, const int* in_sizes, int n_in,
                              void* d_out, int out_size, void* d_ws, size_t ws_size,
                              hipStream_t stream) {
  (void)in_sizes; (void)n_in; (void)out_size; (void)ws_size;
  const float* hs = (const float*)d_in[0];
  const float* Wq = (const float*)d_in[1];
  const float* Wk = (const float*)d_in[2];
  const float* Wv = (const float*)d_in[3];
  const float* Wo = (const float*)d_in[4];
  float* out = (float*)d_out;

  char* ws = (char*)d_ws;
  bf16* hs16 = (bf16*)(ws + 0);              // 8192*2048*2  = 33554432
  bf16* qkv  = (bf16*)(ws + 33554432);       // 8192*3072*2  = 50331648
  bf16* attn = (bf16*)(ws + 83886080);       // 8192*2048*2  = 33554432
  bf16* wq16 = (bf16*)(ws + 117440512);      // 2048*2048*2  = 8388608
  bf16* wk16 = (bf16*)(ws + 125829120);      // 512*2048*2   = 2097152
  bf16* wv16 = (bf16*)(ws + 127926272);      // 512*2048*2   = 2097152
  bf16* wo16 = (bf16*)(ws + 130023424);      // 2048*2048*2  = 8388608
  float* cosT = (float*)(ws + 138412032);    // 8192*32*4    = 1048576
  float* sinT = (float*)(ws + 139460608);    // 8192*32*4    = 1048576

  prep_all<<<27648, 256, 0, stream>>>(hs, Wq, Wk, Wv, Wo,
                                      hs16, wq16, wk16, wv16, wo16, cosT, sinT);

  // QKV projection: M=8192, N=3072, K=2048, RoPE fused; grid 256 = 1 full round
  gemm_qkv<<<dim3(32, 8), 512, 0, stream>>>(hs16, wq16, wk16, wv16, qkv, cosT, sinT);
  attn_sparse<<<dim3(128, 8), 1024, 0, stream>>>(qkv, attn);
  // O projection: M=8192, N=2048, K=2048, fp32 out; grid 256 = 1 full round
  gemm_out<<<dim3(32, 8), 512, 0, stream>>>(attn, wo16, out);
}

// Round 10
// 267.667 us; speedup vs baseline: 1.5899x; 1.1191x over previous
//
#include <hip/hip_runtime.h>
#include <cstdint>
#include <cstddef>

typedef __bf16 bf16;
typedef __attribute__((ext_vector_type(8))) __bf16 bf16x8;
typedef __attribute__((ext_vector_type(4))) __bf16 bf16x4;
typedef __attribute__((ext_vector_type(4))) float f32x4;

#define ATT_SCALE 0.125f   // 1/sqrt(64)

__device__ __forceinline__ f32x4 mfma16(bf16x8 a, bf16x8 b, f32x4 c) {
  return __builtin_amdgcn_mfma_f32_16x16x32_bf16(a, b, c, 0, 0, 0);
}

__device__ __forceinline__ void gload16(const bf16* g, bf16* l) {
  __builtin_amdgcn_global_load_lds((__attribute__((address_space(1))) void*)g,
                                   (__attribute__((address_space(3))) void*)l,
                                   16, 0, 0);
}

// ---------------- fused prep: all fp32->bf16 converts + RoPE table ----------------
__global__ __launch_bounds__(256) void prep_all(const float* __restrict__ hs,
                                                const float* __restrict__ Wq,
                                                const float* __restrict__ Wk,
                                                const float* __restrict__ Wv,
                                                const float* __restrict__ Wo,
                                                bf16* __restrict__ hs16, bf16* __restrict__ wq16,
                                                bf16* __restrict__ wk16, bf16* __restrict__ wv16,
                                                bf16* __restrict__ wo16,
                                                float* __restrict__ cosT, float* __restrict__ sinT) {
  int b = blockIdx.x, t = threadIdx.x;
  const float* src; bf16* dst; int i;
  if (b < 16384)      { src = hs; dst = hs16; i = b * 256 + t; }
  else if (b < 20480) { src = Wq; dst = wq16; i = (b - 16384) * 256 + t; }
  else if (b < 21504) { src = Wk; dst = wk16; i = (b - 20480) * 256 + t; }
  else if (b < 22528) { src = Wv; dst = wv16; i = (b - 21504) * 256 + t; }
  else if (b < 26624) { src = Wo; dst = wo16; i = (b - 22528) * 256 + t; }
  else {
    int idx = (b - 26624) * 256 + t;   // 8192*32
    int tt = idx >> 5, j = idx & 31;
    float inv = exp2f(-(float)j * (13.287712379549449f / 32.0f));
    float fr = (float)tt * inv;
    cosT[idx] = cosf(fr); sinT[idx] = sinf(fr);
    return;
  }
  float4 v = *((const float4*)src + i);
  bf16x4 o;
  o[0] = (bf16)v.x; o[1] = (bf16)v.y; o[2] = (bf16)v.z; o[3] = (bf16)v.w;
  *((bf16x4*)dst + i) = o;
}

// ---------------- QKV GEMM: 256x384 tile, grid (32,8)=256 blocks (zero tail) ------
// (r8 winner, verbatim)
__global__ __launch_bounds__(512) void gemm_qkv(const bf16* __restrict__ A,
                                                const bf16* __restrict__ B0,
                                                const bf16* __restrict__ B1,
                                                const bf16* __restrict__ B2,
                                                bf16* __restrict__ C,
                                                const float* __restrict__ cosT,
                                                const float* __restrict__ sinT) {
  __shared__ bf16 As[3][8192];    // 16 KB per buf
  __shared__ bf16 Bs[3][12288];   // 24 KB per buf
  const int tid = threadIdx.x, lane = tid & 63, wid = tid >> 6;
  const int m0 = blockIdx.x * 256, n0 = blockIdx.y * 384;
  const int wr = wid >> 1, wc = wid & 1;
  const int fr = lane & 15, g4 = lane >> 4;
  const int sw8 = (g4 ^ ((fr >> 1) & 3)) * 8;

  f32x4 acc[4][12] = {};

  auto brow = [&](int n) -> const bf16* {
    if (n < 2048) return B0 + (size_t)n * 2048;
    if (n < 2560) return B1 + (size_t)(n - 2048) * 2048;
    return B2 + (size_t)(n - 2560) * 2048;
  };

  const int ra0 = tid >> 2, ra1 = 128 + (tid >> 2), rb2r = 256 + (tid >> 2);
  const bf16* aS0 = A + (size_t)(m0 + ra0) * 2048 + ((tid & 3) ^ ((ra0 >> 1) & 3)) * 8;
  const bf16* aS1 = A + (size_t)(m0 + ra1) * 2048 + ((tid & 3) ^ ((ra1 >> 1) & 3)) * 8;
  const bf16* bS0 = brow(n0 + ra0) + ((tid & 3) ^ ((ra0 >> 1) & 3)) * 8;
  const bf16* bS1 = brow(n0 + ra1) + ((tid & 3) ^ ((ra1 >> 1) & 3)) * 8;
  const bf16* bS2 = brow(n0 + rb2r) + ((tid & 3) ^ ((rb2r >> 1) & 3)) * 8;
  const int d0 = wid * 512, d1 = 4096 + wid * 512, d2 = 8192 + wid * 512;

#define STQA(BS, KT)  { bf16* d = &As[BS][0]; \
    gload16(aS0 + (KT) * 32, d + d0); gload16(aS1 + (KT) * 32, d + d1); }
#define STQB0(BS, KT) { bf16* d = &Bs[BS][0]; \
    gload16(bS0 + (KT) * 32, d + d0); gload16(bS1 + (KT) * 32, d + d1); }
#define STQB1(BS, KT) { gload16(bS2 + (KT) * 32, &Bs[BS][0] + d2); }

#define QTILE(KT, BI, BS, VM, STG) { \
    asm volatile("s_waitcnt vmcnt(" VM ")" ::: "memory"); \
    __builtin_amdgcn_s_barrier(); \
    __builtin_amdgcn_sched_barrier(0); \
    const bf16* Ab = &As[BI][0]; \
    const bf16* Bb = &Bs[BI][0]; \
    bf16x8 af[4], bfr[4]; \
    _Pragma("unroll") for (int mf = 0; mf < 4; ++mf) \
      af[mf] = *(const bf16x8*)(Ab + (wr * 64 + mf * 16 + fr) * 32 + sw8); \
    _Pragma("unroll") for (int q = 0; q < 4; ++q) \
      bfr[q] = *(const bf16x8*)(Bb + (wc * 192 + q * 16 + fr) * 32 + sw8); \
    if (STG) STQA(BS, (KT) + 2); \
    __builtin_amdgcn_s_setprio(1); \
    _Pragma("unroll") for (int mf = 0; mf < 4; ++mf) \
      _Pragma("unroll") for (int q = 0; q < 4; ++q) \
        acc[mf][q] = mfma16(af[mf], bfr[q], acc[mf][q]); \
    __builtin_amdgcn_s_setprio(0); \
    _Pragma("unroll") for (int q = 0; q < 4; ++q) \
      bfr[q] = *(const bf16x8*)(Bb + (wc * 192 + 64 + q * 16 + fr) * 32 + sw8); \
    if (STG) STQB0(BS, (KT) + 2); \
    __builtin_amdgcn_s_setprio(1); \
    _Pragma("unroll") for (int mf = 0; mf < 4; ++mf) \
      _Pragma("unroll") for (int q = 0; q < 4; ++q) \
        acc[mf][4 + q] = mfma16(af[mf], bfr[q], acc[mf][4 + q]); \
    __builtin_amdgcn_s_setprio(0); \
    _Pragma("unroll") for (int q = 0; q < 4; ++q) \
      bfr[q] = *(const bf16x8*)(Bb + (wc * 192 + 128 + q * 16 + fr) * 32 + sw8); \
    if (STG) STQB1(BS, (KT) + 2); \
    __builtin_amdgcn_s_setprio(1); \
    _Pragma("unroll") for (int mf = 0; mf < 4; ++mf) \
      _Pragma("unroll") for (int q = 0; q < 4; ++q) \
        acc[mf][8 + q] = mfma16(af[mf], bfr[q], acc[mf][8 + q]); \
    __builtin_amdgcn_s_setprio(0); \
  }

  STQA(0, 0); STQB0(0, 0); STQB1(0, 0);
  STQA(1, 1); STQB0(1, 1); STQB1(1, 1);

  int bi = 0, bs = 2;
  for (int kt = 0; kt < 62; ++kt) {
    QTILE(kt, bi, bs, "5", 1)
    bi = (bi == 2) ? 0 : bi + 1;
    bs = (bs == 2) ? 0 : bs + 1;
  }
  QTILE(62, bi, bs, "5", 0)
  bi = (bi == 2) ? 0 : bi + 1;
  QTILE(63, bi, bi, "0", 0)
#undef QTILE
#undef STQA
#undef STQB0
#undef STQB1

  const int fc = lane & 15, fr4 = (lane >> 4) * 4;
#pragma unroll
  for (int mf = 0; mf < 4; ++mf)
#pragma unroll
    for (int i = 0; i < 4; ++i) {
      size_t row = (size_t)(m0 + wr * 64 + mf * 16 + fr4 + i);
      bf16* base = C + row * 3072 + n0 + wc * 192;
      const float* cr = cosT + row * 32;
      const float* sr = sinT + row * 32;
#pragma unroll
      for (int g = 0; g < 3; ++g) {
        if (n0 + wc * 192 + g * 64 < 2560) {
#pragma unroll
          for (int q = 0; q < 2; ++q) {
            int j = q * 16 + fc;
            float c = cr[j], sn = sr[j];
            float x1 = acc[mf][g * 4 + q][i], x2 = acc[mf][g * 4 + q + 2][i];
            base[g * 64 + j]      = (bf16)(x1 * c - x2 * sn);
            base[g * 64 + j + 32] = (bf16)(x2 * c + x1 * sn);
          }
        } else {
#pragma unroll
          for (int q = 0; q < 4; ++q)
            base[g * 64 + q * 16 + fc] = (bf16)acc[mf][g * 4 + q][i];
        }
      }
    }
}

// ---------------- O-proj GEMM: 256x256, 4-buf, 1 barrier/K-tile (r4 winner) -------
__global__ __launch_bounds__(512, 2) void gemm_out(const bf16* __restrict__ A,
                                                   const bf16* __restrict__ B0,
                                                   float* __restrict__ Cout) {
  __shared__ bf16 As[4][8192];
  __shared__ bf16 Bs[4][8192];
  const int tid = threadIdx.x, lane = tid & 63, wid = tid >> 6;
  const int m0 = blockIdx.x * 256, n0 = blockIdx.y * 256;
  const int wr = wid >> 2, wc = wid & 3;
  const int fr = lane & 15, g4 = lane >> 4;
  const int sw8 = (g4 ^ ((fr >> 1) & 3)) * 8;
  const int K = 2048, N = 2048;

  f32x4 acc[8][4] = {};

  const bf16* aS0; const bf16* aS1; const bf16* bS0; const bf16* bS1;
  {
    int c0 = tid, r0 = c0 >> 2, l0 = (c0 & 3) ^ ((r0 >> 1) & 3);
    int c1 = 512 + tid, r1 = c1 >> 2, l1 = (c1 & 3) ^ ((r1 >> 1) & 3);
    aS0 = A + (size_t)(m0 + r0) * K + l0 * 8;
    aS1 = A + (size_t)(m0 + r1) * K + l1 * 8;
    bS0 = B0 + (size_t)(n0 + r0) * K + l0 * 8;
    bS1 = B0 + (size_t)(n0 + r1) * K + l1 * 8;
  }
  const int dst0 = wid * 512;
  const int dst1 = 4096 + wid * 512;

#define STAGE_A(KT) { bf16* d = &As[(KT) & 3][0]; \
    gload16(aS0 + (KT) * 32, d + dst0); gload16(aS1 + (KT) * 32, d + dst1); }
#define STAGE_B(KT) { bf16* d = &Bs[(KT) & 3][0]; \
    gload16(bS0 + (KT) * 32, d + dst0); gload16(bS1 + (KT) * 32, d + dst1); }

#define KTILE(KT, VM, STG) { \
    asm volatile("s_waitcnt vmcnt(" VM ")" ::: "memory"); \
    __builtin_amdgcn_s_barrier(); \
    __builtin_amdgcn_sched_barrier(0); \
    const bf16* Ab = &As[(KT) & 3][0]; \
    const bf16* Bb = &Bs[(KT) & 3][0]; \
    bf16x8 bfr[4], af[4]; \
    _Pragma("unroll") for (int nf = 0; nf < 4; ++nf) \
      bfr[nf] = *(const bf16x8*)(Bb + (wc * 64 + nf * 16 + fr) * 32 + sw8); \
    _Pragma("unroll") for (int mf = 0; mf < 4; ++mf) \
      af[mf] = *(const bf16x8*)(Ab + (wr * 128 + mf * 16 + fr) * 32 + sw8); \
    if (STG) STAGE_A((KT) + 3); \
    __builtin_amdgcn_s_setprio(1); \
    _Pragma("unroll") for (int mf = 0; mf < 4; ++mf) \
      _Pragma("unroll") for (int nf = 0; nf < 4; ++nf) \
        acc[mf][nf] = mfma16(af[mf], bfr[nf], acc[mf][nf]); \
    __builtin_amdgcn_s_setprio(0); \
    _Pragma("unroll") for (int mf = 0; mf < 4; ++mf) \
      af[mf] = *(const bf16x8*)(Ab + (wr * 128 + 64 + mf * 16 + fr) * 32 + sw8); \
    if (STG) STAGE_B((KT) + 3); \
    __builtin_amdgcn_s_setprio(1); \
    _Pragma("unroll") for (int mf = 0; mf < 4; ++mf) \
      _Pragma("unroll") for (int nf = 0; nf < 4; ++nf) \
        acc[4 + mf][nf] = mfma16(af[mf], bfr[nf], acc[4 + mf][nf]); \
    __builtin_amdgcn_s_setprio(0); \
  }

  STAGE_A(0); STAGE_B(0);
  STAGE_A(1); STAGE_B(1);
  STAGE_A(2); STAGE_B(2);

  const int NT = K >> 5;   // 64
  for (int kt = 0; kt < NT - 3; ++kt) KTILE(kt, "8", 1)
  KTILE(NT - 3, "8", 0)
  KTILE(NT - 2, "4", 0)
  KTILE(NT - 1, "0", 0)
#undef KTILE
#undef STAGE_A
#undef STAGE_B

  const int fc = lane & 15, fr4 = (lane >> 4) * 4;
#pragma unroll
  for (int am = 0; am < 8; ++am)
#pragma unroll
    for (int i = 0; i < 4; ++i) {
      size_t row = (size_t)(m0 + wr * 128 + am * 16 + fr4 + i);
#pragma unroll
      for (int nf = 0; nf < 4; ++nf) {
        int col = n0 + wc * 64 + nf * 16 + fc;
        Cout[row * (size_t)N + col] = acc[am][nf][i];
      }
    }
}

// ---------------- block-sparse attention v2: permuted-key, no P round-trip --------
// grid (128 qblocks, 16), 512 threads = 8 waves = 2 heads x 4 rowgroups.
// blockIdx.y: kv = y>>1, pair = y&1; head = kv*4 + pair*2 + (wid>>2).
// K staged in PERMUTED row order pi(p)=32*(p>>5)+((p&15)>>2)*8+((p>>4)&1)*4+(p&3)
// so QK^T output slots {s[0],s[1]} are exactly PV's pa0 keys (g4*8..+7) and
// {s[2],s[3]} are pa1 (32+g4*8..+7): P->A-operand is a pure in-register bf16 cvt.
// V staged logically (keys in order) -> B-operand slots match.
// Ks and Vt both double-buffered -> ONE __syncthreads per KV step.
// LDS 34 KB -> 4 blocks/CU (32 waves). Scale folded into exp via fmaf.
__global__ __launch_bounds__(512) void attn_sparse(const bf16* __restrict__ qkv,
                                                   bf16* __restrict__ attn) {
  const int iblk = blockIdx.x;
  const int kv = blockIdx.y >> 1, pr = blockIdx.y & 1;
  const int tid = threadIdx.x, lane = tid & 63, wid = tid >> 6;
  const int h = kv * 4 + pr * 2 + (wid >> 2);
  const int rg = wid & 3;

  __shared__ bf16 Ks[2][64 * 64];   // permuted rows, XOR slot swizzle
  __shared__ bf16 Vt[2][64 * 72];   // Vt[d][key], logical order

  const int qcol = h * 64, kcol = 2048 + kv * 64, vcol = 2560 + kv * 64;
  const size_t trow0 = (size_t)iblk * 64;
  const int fr = lane & 15, g4 = lane >> 4, fk = g4 * 8, fr4 = g4 * 4;

  // Q fragments (B-operand of swapped QK^T)
  const bf16* qrow = qkv + (trow0 + rg * 16 + fr) * 3072 + qcol;
  bf16x8 bq0 = *(const bf16x8*)(qrow + fk);
  bf16x8 bq1 = *(const bf16x8*)(qrow + 32 + fk);

  float mrun = -INFINITY, lrun = 0.f;
  f32x4 acc[4] = {};

  // K staging: physical row kr, slot ks; logical source row pi(kr)
  const int kr = tid >> 3, ks = tid & 7;
  const int pik = ((kr >> 5) << 5) + (((kr & 15) >> 2) << 3) + (((kr >> 4) & 1) << 2) + (kr & 3);
  const int kso = ((ks ^ (kr & 7)) * 8);
  // V staging: pair vp, d-group vd0 (512 threads exactly cover 32x16)
  const int vp = tid & 31, vd0 = (tid >> 5) * 4;

  // logical-key bases for mask: key(n,i) = kb[n] + i
  const int kb0m = fk, kb1m = fk + 4, kb2m = fk + 32, kb3m = fk + 36;

  const int nsel = (iblk < 8) ? (iblk + 1) : 9;
  auto jof = [&](int js) { return (iblk < 8) ? js : ((js == 0) ? 0 : iblk - 8 + js); };

  // prologue: stage K(0), V(0) into buf 0
  {
    const size_t krow = (size_t)jof(0) * 64;
    gload16(qkv + (krow + pik) * 3072 + kcol + kso, &Ks[0][0] + (tid >> 6) * 512);
    const bf16* v0p = qkv + (krow + 2 * vp) * 3072 + vcol + vd0;
    uint64_t a = *(const uint64_t*)v0p;
    uint64_t b = *(const uint64_t*)(v0p + 3072);
#pragma unroll
    for (int e = 0; e < 4; ++e) {
      uint32_t w = (uint32_t)((a >> (16 * e)) & 0xFFFF) |
                   ((uint32_t)((b >> (16 * e)) & 0xFFFF) << 16);
      *(uint32_t*)(&Vt[0][0] + (vd0 + e) * 72 + 2 * vp) = w;
    }
  }
  __syncthreads();

  for (int js = 0; js < nsel; ++js) {
    const int cur = js & 1;
    const int jblk = jof(js);
    const bool pre = (js + 1 < nsel);
    const size_t nrow = pre ? (size_t)jof(js + 1) * 64 : 0;

    // issue V(j+1) global loads early — latency hides under QK^T/softmax
    uint64_t va = 0, vb2 = 0;
    if (pre) {
      const bf16* v0p = qkv + (nrow + 2 * vp) * 3072 + vcol + vd0;
      va = *(const uint64_t*)v0p;
      vb2 = *(const uint64_t*)(v0p + 3072);
    }

    // S^T = K Q^T from Ks[cur] (physical rows; lane -> 16 scores of q-row fr)
    f32x4 s[4];
    __builtin_amdgcn_s_setprio(1);
#pragma unroll
    for (int n = 0; n < 4; ++n) {
      const char* krowp = (const char*)&Ks[cur][0] + (n * 16 + fr) * 128;
      bf16x8 ka = *(const bf16x8*)(krowp + ((g4 ^ (fr & 7)) << 4));
      bf16x8 kc = *(const bf16x8*)(krowp + (((4 + g4) ^ (fr & 7)) << 4));
      f32x4 z = {};
      z = mfma16(ka, bq0, z);
      s[n] = mfma16(kc, bq1, z);
    }
    __builtin_amdgcn_s_setprio(0);

    // stage K(j+1) -> Ks[cur^1] (WAR-safe: last read in js-1, behind prev barrier)
    if (pre)
      gload16(qkv + (nrow + pik) * 3072 + kcol + kso, &Ks[cur ^ 1][0] + (tid >> 6) * 512);

    // causal mask (diag block only), raw scores; keys are logical
    if (jblk == iblk) {
      const int qr = rg * 16 + fr;
#pragma unroll
      for (int i = 0; i < 4; ++i) {
        if (kb0m + i > qr) s[0][i] = -1e30f;
        if (kb1m + i > qr) s[1][i] = -1e30f;
        if (kb2m + i > qr) s[2][i] = -1e30f;
        if (kb3m + i > qr) s[3][i] = -1e30f;
      }
    }

    // online softmax (scale folded into exp)
    float t0 = fmaxf(fmaxf(s[0][0], s[0][1]), fmaxf(s[0][2], s[0][3]));
    float t1 = fmaxf(fmaxf(s[1][0], s[1][1]), fmaxf(s[1][2], s[1][3]));
    float t2 = fmaxf(fmaxf(s[2][0], s[2][1]), fmaxf(s[2][2], s[2][3]));
    float t3 = fmaxf(fmaxf(s[3][0], s[3][1]), fmaxf(s[3][2], s[3][3]));
    float mx = fmaxf(fmaxf(t0, t1), fmaxf(t2, t3));
    mx = fmaxf(mx, __shfl_xor(mx, 16, 64));
    mx = fmaxf(mx, __shfl_xor(mx, 32, 64));
    float mnew = fmaxf(mrun, mx);
    float corr = __expf((mrun - mnew) * ATT_SCALE);
    mrun = mnew;
    const float msc = mnew * ATT_SCALE;
    float ps = 0.f;
#pragma unroll
    for (int n = 0; n < 4; ++n) {
      float p0 = __expf(fmaf(s[n][0], ATT_SCALE, -msc));
      float p1 = __expf(fmaf(s[n][1], ATT_SCALE, -msc));
      float p2 = __expf(fmaf(s[n][2], ATT_SCALE, -msc));
      float p3 = __expf(fmaf(s[n][3], ATT_SCALE, -msc));
      s[n][0] = p0; s[n][1] = p1; s[n][2] = p2; s[n][3] = p3;
      ps += (p0 + p1) + (p2 + p3);
    }
    ps += __shfl_xor(ps, 16, 64);
    ps += __shfl_xor(ps, 32, 64);
    lrun = lrun * corr + ps;

    // rescale acc rows (q = fr4+i; corr uniform across g4 groups for same fr)
    float cq[4];
#pragma unroll
    for (int i = 0; i < 4; ++i) cq[i] = __shfl(corr, fr4 + i, 64);
#pragma unroll
    for (int n = 0; n < 4; ++n)
#pragma unroll
      for (int i = 0; i < 4; ++i) acc[n][i] *= cq[i];

    // P -> A-operand: pure in-register cvt (permuted-key layout)
    bf16x8 pa0, pa1;
#pragma unroll
    for (int i = 0; i < 4; ++i) {
      pa0[i]     = (bf16)s[0][i];
      pa0[4 + i] = (bf16)s[1][i];
      pa1[i]     = (bf16)s[2][i];
      pa1[4 + i] = (bf16)s[3][i];
    }

    // write V(j+1) regs -> Vt[cur^1] (late write; WAR-safe behind prev barrier)
    if (pre) {
#pragma unroll
      for (int e = 0; e < 4; ++e) {
        uint32_t w = (uint32_t)((va >> (16 * e)) & 0xFFFF) |
                     ((uint32_t)((vb2 >> (16 * e)) & 0xFFFF) << 16);
        *(uint32_t*)(&Vt[cur ^ 1][0] + (vd0 + e) * 72 + 2 * vp) = w;
      }
    }

    // PV: O += P @ V from Vt[cur]
    __builtin_amdgcn_s_setprio(1);
#pragma unroll
    for (int n = 0; n < 4; ++n) {
      bf16x8 vb0 = *(const bf16x8*)(&Vt[cur][0] + (n * 16 + fr) * 72 + fk);
      bf16x8 vb1 = *(const bf16x8*)(&Vt[cur][0] + (n * 16 + fr) * 72 + 32 + fk);
      acc[n] = mfma16(pa0, vb0, acc[n]);
      acc[n] = mfma16(pa1, vb1, acc[n]);
    }
    __builtin_amdgcn_s_setprio(0);

    __syncthreads();   // drains K(j+1) gload_lds + Vt writes; frees Ks/Vt[cur]
  }

  // epilogue: normalize and store bf16
  float lq[4];
#pragma unroll
  for (int i = 0; i < 4; ++i) lq[i] = __shfl(lrun, fr4 + i, 64);
#pragma unroll
  for (int i = 0; i < 4; ++i) {
    float rl = 1.0f / lq[i];
    size_t t = trow0 + rg * 16 + fr4 + i;
#pragma unroll
    for (int n = 0; n < 4; ++n)
      attn[t * 2048 + h * 64 + n * 16 + fr] = (bf16)(acc[n][i] * rl);
  }
}

// ---------------- launch ----------------
extern "C" void kernel_launch(void* const* d_in, const int* in_sizes, int n_in,
                              void* d_out, int out_size, void* d_ws, size_t ws_size,
                              hipStream_t stream) {
  (void)in_sizes; (void)n_in; (void)out_size; (void)ws_size;
  const float* hs = (const float*)d_in[0];
  const float* Wq = (const float*)d_in[1];
  const float* Wk = (const float*)d_in[2];
  const float* Wv = (const float*)d_in[3];
  const float* Wo = (const float*)d_in[4];
  float* out = (float*)d_out;

  char* ws = (char*)d_ws;
  bf16* hs16 = (bf16*)(ws + 0);              // 8192*2048*2  = 33554432
  bf16* qkv  = (bf16*)(ws + 33554432);       // 8192*3072*2  = 50331648
  bf16* attn = (bf16*)(ws + 83886080);       // 8192*2048*2  = 33554432
  bf16* wq16 = (bf16*)(ws + 117440512);      // 2048*2048*2  = 8388608
  bf16* wk16 = (bf16*)(ws + 125829120);      // 512*2048*2   = 2097152
  bf16* wv16 = (bf16*)(ws + 127926272);      // 512*2048*2   = 2097152
  bf16* wo16 = (bf16*)(ws + 130023424);      // 2048*2048*2  = 8388608
  float* cosT = (float*)(ws + 138412032);    // 8192*32*4    = 1048576
  float* sinT = (float*)(ws + 139460608);    // 8192*32*4    = 1048576

  prep_all<<<27648, 256, 0, stream>>>(hs, Wq, Wk, Wv, Wo,
                                      hs16, wq16, wk16, wv16, wo16, cosT, sinT);

  // QKV projection: M=8192, N=3072, K=2048, RoPE fused; grid 256 = 1 full round
  gemm_qkv<<<dim3(32, 8), 512, 0, stream>>>(hs16, wq16, wk16, wv16, qkv, cosT, sinT);
  attn_sparse<<<dim3(128, 16), 512, 0, stream>>>(qkv, attn);
  // O projection: M=8192, N=2048, K=2048, fp32 out; grid 256 = 1 full round
  gemm_out<<<dim3(32, 8), 512, 0, stream>>>(attn, wo16, out);
}